// Round 12
// baseline (386.784 us; speedup 1.0000x reference)
//
#include <hip/hip_runtime.h>

// ConvCapsMatrix EM routing, MI355X. Inputs FP32, output FP32.
// R12: LDS 62->43.5 KB (single reused partial buffer, two-phase S1/S2
// reduction) -> 3 blocks/CU -> all 576 blocks co-resident (R10 ran as
// 512 + 64-block tail = 2 full rounds). j-loop reverted to single-n
// (R11's 2-way interleave cost VGPR 64->100, occupancy 29->17%).
// One workgroup per position (576 x 512), thread=(o=t&31, ng=t>>5).

#define NN    288
#define EPSV  1e-8f

__device__ __forceinline__ void compute_votes(const float* __restrict__ Wt,
                                              const float* __restrict__ xp_s,
                                              int n, int o, float* __restrict__ V)
{
  // W[k,l,c,o,y,z] flat = (n*32+o)*16 + y*4+z
  float Wf[16];
  {
    const float* wp = Wt + (((n << 5) + o) << 4);
#pragma unroll
    for (int i = 0; i < 4; ++i) {
      const float4 q = *(const float4*)(wp + (i << 2));
      Wf[i*4+0]=q.x; Wf[i*4+1]=q.y; Wf[i*4+2]=q.z; Wf[i*4+3]=q.w;
    }
  }
  float xv[16];
  {
    const float* xr = xp_s + (n << 4);
#pragma unroll
    for (int i = 0; i < 4; ++i) {
      const float4 q = *(const float4*)(xr + (i << 2));
      xv[i*4+0]=q.x; xv[i*4+1]=q.y; xv[i*4+2]=q.z; xv[i*4+3]=q.w;
    }
  }
#pragma unroll
  for (int xi = 0; xi < 4; ++xi)
#pragma unroll
    for (int z = 0; z < 4; ++z)
      V[xi*4+z] = fmaf(xv[xi*4+0], Wf[z],
                  fmaf(xv[xi*4+1], Wf[4+z],
                  fmaf(xv[xi*4+2], Wf[8+z],
                       xv[xi*4+3]* Wf[12+z])));
}

__global__ __launch_bounds__(512, 6) void caps_em_kernel(
    const float* __restrict__ X, const float* __restrict__ A, const float* __restrict__ Wt,
    const float* __restrict__ Bu, const float* __restrict__ Ba,
    float* __restrict__ Out)
{
  __shared__ float xp_s[NN*16];   // patch poses                 18432 B
  __shared__ float a_s[NN];       // patch activations            1152 B
  __shared__ float part[8*544];   // per-wave partials, 2-phase  17408 B
  __shared__ float prs[8*32];     // per-wave sum Ra              1024 B
  __shared__ float mu_t[512];     // mu[p][o]                     2048 B
  __shared__ float isig_t[512];   // 1/sig2[p][o]                 2048 B
  __shared__ float lsig_t[512];   // log sig2[p][o]               2048 B
  __shared__ float la_s[32];      // log(a_out+eps)
  __shared__ float slog_s[32];    // sum_p log sig2
  __shared__ float aout_s[32];    // total ~43.5 KB -> 3 blocks/CU

  const int t    = threadIdx.x;
  const int o    = t & 31;
  const int ng   = t >> 5;        // 0..15
  const int wv   = t >> 6;        // 0..7
  const int lane = t & 63;

  const int pos = blockIdx.x;
  const int b  = pos / 144;
  const int r_ = pos - b*144;
  const int h  = r_ / 12;
  const int w  = r_ - (r_/12)*12;

  // ---- stage pose patch: x[b,h+k,w+l,c,p] -> xp_s[(kl*32+c)*16+p]
  for (int i = t; i < 1152; i += 512) {
    const int e   = i << 2;
    const int kl  = e >> 9;
    const int rem = e & 511;
    const int hy = h + kl/3, wx = w + (kl - (kl/3)*3);
    const float4 q = *(const float4*)(X + ((((b*14 + hy)*14 + wx) << 9) + rem));
    *(float4*)(xp_s + (kl << 9) + rem) = q;
  }
  for (int i = t; i < NN; i += 512) {
    const int kl = i >> 5, c = i & 31;
    const int hy = h + kl/3, wx = w + (kl - (kl/3)*3);
    a_s[i] = A[((b*14 + hy)*14 + wx)*32 + c];
  }
  __syncthreads();

  // per-thread cached routing state (o fixed per thread)
  float mu_r[16], isig_r[16];
  float la_r = 0.f, slog_r = 0.f;
#pragma unroll
  for (int p = 0; p < 16; ++p) { mu_r[p] = 0.f; isig_r[p] = 0.f; }

  for (int it = 0; it < 3; ++it) {
    // ========== fused stats pass: Ra, sum Ra*V, sum Ra*V^2 ==========
    float S1[16], S2[16];
#pragma unroll
    for (int p = 0; p < 16; ++p) { S1[p] = 0.f; S2[p] = 0.f; }
    float rs = 0.f;

#pragma unroll 1
    for (int j = 0; j < 18; ++j) {
      const int n = ng + (j << 4);
      float V[16];
      compute_votes(Wt, xp_s, n, o, V);

      float ra;
      if (it == 0) {
        ra = a_s[n] * (1.0f/32.0f);
      } else {
        // logp = -0.5 * ( sum_p (V-mu)^2*isig + slog )
        float q = slog_r;
#pragma unroll
        for (int p = 0; p < 16; ++p) {
          const float d = V[p] - mu_r[p];
          q = fmaf(d*d, isig_r[p], q);
        }
        float z = la_r - 0.5f*q;
        // softmax over the 32 o's (one half-wave holds all o for this n)
        float m = z;
#pragma unroll
        for (int msk = 16; msk >= 1; msk >>= 1) m = fmaxf(m, __shfl_xor(m, msk));
        float ev = __expf(z - m);
        float s = ev;
#pragma unroll
        for (int msk = 16; msk >= 1; msk >>= 1) s += __shfl_xor(s, msk);
        ra = (ev / s) * a_s[n];
      }
      rs += ra;
#pragma unroll
      for (int p = 0; p < 16; ++p) {
        const float rv = ra * V[p];
        S1[p] += rv;
        S2[p] = fmaf(rv, V[p], S2[p]);
      }
    }

    // ---- pair-combine ng via lane^32
#pragma unroll
    for (int p = 0; p < 16; ++p) {
      S1[p] += __shfl_xor(S1[p], 32);
      S2[p] += __shfl_xor(S2[p], 32);
    }
    rs += __shfl_xor(rs, 32);

    // ---- phase A: S1 partials -> mu
    if (lane < 32) {
      float* p1 = part + wv*544 + o*17;
#pragma unroll
      for (int p = 0; p < 16; ++p) p1[p] = S1[p];
      prs[wv*32 + o] = rs;
    }
    __syncthreads();
    {
      const int pi = t >> 5, oo = t & 31;   // 512 threads cover all (p,o)
      float s1 = 0.f, rsum = EPSV;
#pragma unroll
      for (int g = 0; g < 8; ++g) {
        s1   += part[g*544 + oo*17 + pi];
        rsum += prs[(g << 5) + oo];
      }
      mu_t[pi*32 + oo] = s1 / rsum;
    }
    __syncthreads();

    // ---- phase B: S2 partials -> sig2 (var = s2/rs - mu^2, clamped)
    if (lane < 32) {
      float* p2 = part + wv*544 + o*17;
#pragma unroll
      for (int p = 0; p < 16; ++p) p2[p] = S2[p];
    }
    __syncthreads();
    {
      const int pi = t >> 5, oo = t & 31;
      float s2 = 0.f, rsum = EPSV;
#pragma unroll
      for (int g = 0; g < 8; ++g) {
        s2   += part[g*544 + oo*17 + pi];
        rsum += prs[(g << 5) + oo];
      }
      const float mu = mu_t[pi*32 + oo];
      float var = s2 / rsum - mu*mu;
      var = fmaxf(var, 0.f);
      const float sg = var + EPSV;
      isig_t[pi*32 + oo] = 1.0f / sg;
      lsig_t[pi*32 + oo] = __logf(sg);
    }
    __syncthreads();

    // ---- E2: cost, a_out per o
    if (t < 32) {
      float rsum = EPSV;
#pragma unroll
      for (int g = 0; g < 8; ++g) rsum += prs[(g << 5) + t];
      float slog = 0.f;
#pragma unroll
      for (int p = 0; p < 16; ++p) slog += lsig_t[p*32 + t];
      const float bu = Bu[t];
      const float ba = Ba[t];
      const float cost = rsum * (16.0f*bu + 0.5f*slog);
      const float av = 1.0f / (1.0f + __expf(-(ba - cost)));   // LAM=1
      aout_s[t] = av;
      la_s[t]   = __logf(av + EPSV);
      slog_s[t] = slog;
    }
    __syncthreads();

    if (it < 2) {
#pragma unroll
      for (int p = 0; p < 16; ++p) {
        mu_r[p]   = mu_t[p*32 + o];
        isig_r[p] = isig_t[p*32 + o];
      }
      slog_r = slog_s[o];
      la_r   = la_s[o];
    }
  }

  // ---- outputs (fp32): pose = mu (B,Ho,Wo,OC,M,M) then a_out (B,Ho,Wo,OC)
  {
    const int oo = t >> 4, pi = t & 15;     // t < 512
    Out[pos*512 + t] = mu_t[pi*32 + oo];
  }
  if (t < 32) Out[294912 + pos*32 + t] = aout_s[t];
}

extern "C" void kernel_launch(void* const* d_in, const int* in_sizes, int n_in,
                              void* d_out, int out_size, void* d_ws, size_t ws_size,
                              hipStream_t stream) {
  (void)in_sizes; (void)n_in; (void)d_ws; (void)ws_size; (void)out_size;
  const float* X  = (const float*)d_in[0];
  const float* A  = (const float*)d_in[1];
  const float* Wt = (const float*)d_in[2];
  const float* Bu = (const float*)d_in[3];
  const float* Ba = (const float*)d_in[4];
  float* Out = (float*)d_out;
  hipLaunchKernelGGL(caps_em_kernel, dim3(576), dim3(512), 0, stream,
                     X, A, Wt, Bu, Ba, Out);
}

// Round 13
// 177.414 us; speedup vs baseline: 2.1801x; 2.1801x over previous
//
#include <hip/hip_runtime.h>

// ConvCapsMatrix EM routing, MI355X. Inputs FP32, output FP32.
// R13 = R12's two-phase LDS reduction (43.5 KB -> 3 blocks/CU co-residency)
// with R10's __launch_bounds__(512,4). R12's (512,6) forced VGPR 40 + scratch
// spills (FETCH 11->675 MB, 335 us). The compiler's natural ~64-80 VGPR at
// cap-128 keeps 6 waves/SIMD feasible (<=85) without spilling.
// One workgroup per position (576 x 512), thread=(o=t&31, ng=t>>5).

#define NN    288
#define EPSV  1e-8f

__device__ __forceinline__ void compute_votes(const float* __restrict__ Wt,
                                              const float* __restrict__ xp_s,
                                              int n, int o, float* __restrict__ V)
{
  // W[k,l,c,o,y,z] flat = (n*32+o)*16 + y*4+z
  float Wf[16];
  {
    const float* wp = Wt + (((n << 5) + o) << 4);
#pragma unroll
    for (int i = 0; i < 4; ++i) {
      const float4 q = *(const float4*)(wp + (i << 2));
      Wf[i*4+0]=q.x; Wf[i*4+1]=q.y; Wf[i*4+2]=q.z; Wf[i*4+3]=q.w;
    }
  }
  float xv[16];
  {
    const float* xr = xp_s + (n << 4);
#pragma unroll
    for (int i = 0; i < 4; ++i) {
      const float4 q = *(const float4*)(xr + (i << 2));
      xv[i*4+0]=q.x; xv[i*4+1]=q.y; xv[i*4+2]=q.z; xv[i*4+3]=q.w;
    }
  }
#pragma unroll
  for (int xi = 0; xi < 4; ++xi)
#pragma unroll
    for (int z = 0; z < 4; ++z)
      V[xi*4+z] = fmaf(xv[xi*4+0], Wf[z],
                  fmaf(xv[xi*4+1], Wf[4+z],
                  fmaf(xv[xi*4+2], Wf[8+z],
                       xv[xi*4+3]* Wf[12+z])));
}

__global__ __launch_bounds__(512, 4) void caps_em_kernel(
    const float* __restrict__ X, const float* __restrict__ A, const float* __restrict__ Wt,
    const float* __restrict__ Bu, const float* __restrict__ Ba,
    float* __restrict__ Out)
{
  __shared__ float xp_s[NN*16];   // patch poses                 18432 B
  __shared__ float a_s[NN];       // patch activations            1152 B
  __shared__ float part[8*544];   // per-wave partials, 2-phase  17408 B
  __shared__ float prs[8*32];     // per-wave sum Ra              1024 B
  __shared__ float mu_t[512];     // mu[p][o]                     2048 B
  __shared__ float isig_t[512];   // 1/sig2[p][o]                 2048 B
  __shared__ float lsig_t[512];   // log sig2[p][o]               2048 B
  __shared__ float la_s[32];      // log(a_out+eps)
  __shared__ float slog_s[32];    // sum_p log sig2
  __shared__ float aout_s[32];    // total ~43.5 KB -> 3 blocks/CU

  const int t    = threadIdx.x;
  const int o    = t & 31;
  const int ng   = t >> 5;        // 0..15
  const int wv   = t >> 6;        // 0..7
  const int lane = t & 63;

  const int pos = blockIdx.x;
  const int b  = pos / 144;
  const int r_ = pos - b*144;
  const int h  = r_ / 12;
  const int w  = r_ - (r_/12)*12;

  // ---- stage pose patch: x[b,h+k,w+l,c,p] -> xp_s[(kl*32+c)*16+p]
  for (int i = t; i < 1152; i += 512) {
    const int e   = i << 2;
    const int kl  = e >> 9;
    const int rem = e & 511;
    const int hy = h + kl/3, wx = w + (kl - (kl/3)*3);
    const float4 q = *(const float4*)(X + ((((b*14 + hy)*14 + wx) << 9) + rem));
    *(float4*)(xp_s + (kl << 9) + rem) = q;
  }
  for (int i = t; i < NN; i += 512) {
    const int kl = i >> 5, c = i & 31;
    const int hy = h + kl/3, wx = w + (kl - (kl/3)*3);
    a_s[i] = A[((b*14 + hy)*14 + wx)*32 + c];
  }
  __syncthreads();

  // per-thread cached routing state (o fixed per thread)
  float mu_r[16], isig_r[16];
  float la_r = 0.f, slog_r = 0.f;
#pragma unroll
  for (int p = 0; p < 16; ++p) { mu_r[p] = 0.f; isig_r[p] = 0.f; }

  for (int it = 0; it < 3; ++it) {
    // ========== fused stats pass: Ra, sum Ra*V, sum Ra*V^2 ==========
    float S1[16], S2[16];
#pragma unroll
    for (int p = 0; p < 16; ++p) { S1[p] = 0.f; S2[p] = 0.f; }
    float rs = 0.f;

#pragma unroll 1
    for (int j = 0; j < 18; ++j) {
      const int n = ng + (j << 4);
      float V[16];
      compute_votes(Wt, xp_s, n, o, V);

      float ra;
      if (it == 0) {
        ra = a_s[n] * (1.0f/32.0f);
      } else {
        // logp = -0.5 * ( sum_p (V-mu)^2*isig + slog )
        float q = slog_r;
#pragma unroll
        for (int p = 0; p < 16; ++p) {
          const float d = V[p] - mu_r[p];
          q = fmaf(d*d, isig_r[p], q);
        }
        float z = la_r - 0.5f*q;
        // softmax over the 32 o's (one half-wave holds all o for this n)
        float m = z;
#pragma unroll
        for (int msk = 16; msk >= 1; msk >>= 1) m = fmaxf(m, __shfl_xor(m, msk));
        float ev = __expf(z - m);
        float s = ev;
#pragma unroll
        for (int msk = 16; msk >= 1; msk >>= 1) s += __shfl_xor(s, msk);
        ra = (ev / s) * a_s[n];
      }
      rs += ra;
#pragma unroll
      for (int p = 0; p < 16; ++p) {
        const float rv = ra * V[p];
        S1[p] += rv;
        S2[p] = fmaf(rv, V[p], S2[p]);
      }
    }

    // ---- pair-combine ng via lane^32
#pragma unroll
    for (int p = 0; p < 16; ++p) {
      S1[p] += __shfl_xor(S1[p], 32);
      S2[p] += __shfl_xor(S2[p], 32);
    }
    rs += __shfl_xor(rs, 32);

    // ---- phase A: S1 partials -> mu
    if (lane < 32) {
      float* p1 = part + wv*544 + o*17;
#pragma unroll
      for (int p = 0; p < 16; ++p) p1[p] = S1[p];
      prs[wv*32 + o] = rs;
    }
    __syncthreads();
    {
      const int pi = t >> 5, oo = t & 31;   // 512 threads cover all (p,o)
      float s1 = 0.f, rsum = EPSV;
#pragma unroll
      for (int g = 0; g < 8; ++g) {
        s1   += part[g*544 + oo*17 + pi];
        rsum += prs[(g << 5) + oo];
      }
      mu_t[pi*32 + oo] = s1 / rsum;
    }
    __syncthreads();

    // ---- phase B: S2 partials -> sig2 (var = s2/rs - mu^2, clamped)
    if (lane < 32) {
      float* p2 = part + wv*544 + o*17;
#pragma unroll
      for (int p = 0; p < 16; ++p) p2[p] = S2[p];
    }
    __syncthreads();
    {
      const int pi = t >> 5, oo = t & 31;
      float s2 = 0.f, rsum = EPSV;
#pragma unroll
      for (int g = 0; g < 8; ++g) {
        s2   += part[g*544 + oo*17 + pi];
        rsum += prs[(g << 5) + oo];
      }
      const float mu = mu_t[pi*32 + oo];
      float var = s2 / rsum - mu*mu;
      var = fmaxf(var, 0.f);
      const float sg = var + EPSV;
      isig_t[pi*32 + oo] = 1.0f / sg;
      lsig_t[pi*32 + oo] = __logf(sg);
    }
    __syncthreads();

    // ---- E2: cost, a_out per o
    if (t < 32) {
      float rsum = EPSV;
#pragma unroll
      for (int g = 0; g < 8; ++g) rsum += prs[(g << 5) + t];
      float slog = 0.f;
#pragma unroll
      for (int p = 0; p < 16; ++p) slog += lsig_t[p*32 + t];
      const float bu = Bu[t];
      const float ba = Ba[t];
      const float cost = rsum * (16.0f*bu + 0.5f*slog);
      const float av = 1.0f / (1.0f + __expf(-(ba - cost)));   // LAM=1
      aout_s[t] = av;
      la_s[t]   = __logf(av + EPSV);
      slog_s[t] = slog;
    }
    __syncthreads();

    if (it < 2) {
#pragma unroll
      for (int p = 0; p < 16; ++p) {
        mu_r[p]   = mu_t[p*32 + o];
        isig_r[p] = isig_t[p*32 + o];
      }
      slog_r = slog_s[o];
      la_r   = la_s[o];
    }
  }

  // ---- outputs (fp32): pose = mu (B,Ho,Wo,OC,M,M) then a_out (B,Ho,Wo,OC)
  {
    const int oo = t >> 4, pi = t & 15;     // t < 512
    Out[pos*512 + t] = mu_t[pi*32 + oo];
  }
  if (t < 32) Out[294912 + pos*32 + t] = aout_s[t];
}

extern "C" void kernel_launch(void* const* d_in, const int* in_sizes, int n_in,
                              void* d_out, int out_size, void* d_ws, size_t ws_size,
                              hipStream_t stream) {
  (void)in_sizes; (void)n_in; (void)d_ws; (void)ws_size; (void)out_size;
  const float* X  = (const float*)d_in[0];
  const float* A  = (const float*)d_in[1];
  const float* Wt = (const float*)d_in[2];
  const float* Bu = (const float*)d_in[3];
  const float* Ba = (const float*)d_in[4];
  float* Out = (float*)d_out;
  hipLaunchKernelGGL(caps_em_kernel, dim3(576), dim3(512), 0, stream,
                     X, A, Wt, Bu, Ba, Out);
}